// Round 8
// baseline (974.178 us; speedup 1.0000x reference)
//
#include <hip/hip_runtime.h>
#include <hip/hip_bf16.h>

#define BB 8
#define NN 2048
#define MM (BB*NN)
#define KNN 32
#define TI 16

typedef __bf16 bf16x8 __attribute__((ext_vector_type(8)));
typedef float  f32x4  __attribute__((ext_vector_type(4)));

// ---------------------------------------------------------------- dtype detect
__global__ void detect_dtype_kernel(const unsigned short* __restrict__ p,
                                    int n16, int* __restrict__ flag) {
    __shared__ int cnt;
    if (threadIdx.x == 0) cnt = 0;
    __syncthreads();
    int local = 0;
    for (int i = threadIdx.x; i < n16; i += 256) {
        int e = (p[i] >> 7) & 0xFF;
        if (e >= 132) local++;     // |v| >= 2^5, or inf/nan
    }
    atomicAdd(&cnt, local);
    __syncthreads();
    if (threadIdx.x == 0) *flag = (cnt > 100) ? 1 : 0;   // 1 = fp32 inputs
}

// ---------------------------------------------------------------- diagnostic
__global__ void diag_fill_kernel(__hip_bfloat16* __restrict__ out, int n, float marker) {
    int i = blockIdx.x * 256 + threadIdx.x;
    if (i < n) out[i] = __float2bfloat16(marker);
}

// ---------------------------------------------------------------- utilities
__global__ void upcast_kernel(const void* __restrict__ in, float* __restrict__ out,
                              int n, const int* __restrict__ flag) {
    int f32 = *flag;
    int i = blockIdx.x * 256 + threadIdx.x;
    if (i < n)
        out[i] = f32 ? ((const float*)in)[i]
                     : __bfloat162float(((const __hip_bfloat16*)in)[i]);
}

// W: (2C, Cout) -> Wa = Wtop - Wbot, Wc = Wbot (C x Cout fp32), bf = bias.
// EdgeConv decomposition:
//   max_j act([x_i, x_j - x_i] W + b) = act(x_i Wa + b + max_j (x_j Wc))
__global__ void prep_w_kernel(const void* __restrict__ W, const void* __restrict__ bvec,
                              float* __restrict__ Wa, float* __restrict__ Wc,
                              float* __restrict__ bf, int C, int Cout,
                              const int* __restrict__ flag) {
    int f32 = *flag;
    int total = C * Cout;
    int gid = blockIdx.x * 256 + threadIdx.x;
    for (int t = gid; t < total; t += gridDim.x * 256) {
        int k = t / Cout, n = t % Cout;
        float top, bot;
        if (f32) {
            top = ((const float*)W)[k * Cout + n];
            bot = ((const float*)W)[(C + k) * Cout + n];
        } else {
            top = __bfloat162float(((const __hip_bfloat16*)W)[k * Cout + n]);
            bot = __bfloat162float(((const __hip_bfloat16*)W)[(C + k) * Cout + n]);
        }
        Wa[t] = top - bot;
        Wc[t] = bot;
    }
    if (gid < Cout)
        bf[gid] = f32 ? ((const float*)bvec)[gid]
                      : __bfloat162float(((const __hip_bfloat16*)bvec)[gid]);
}

__global__ void sqnorm_kernel(const float* __restrict__ X, float* __restrict__ sq, int C) {
    int row = blockIdx.x * 256 + threadIdx.x;
    if (row < MM) {
        float s = 0.f;
        for (int c = 0; c < C; c++) { float v = X[(size_t)row * C + c]; s += v * v; }
        sq[row] = s;
    }
}

// ---------------------------------------------------------------- bf16 3-way split
// x = h + m + l with each limb bf16 (RNE); residual ~2^-27 relative.
// Products kept: hh (full magnitude) + hm,mh,hl,lh,mm (<= 2^-9 magnitude).
__device__ __forceinline__ unsigned short f2bf(float f) {
    unsigned u = __float_as_uint(f);
    unsigned r = (u + 0x7FFF + ((u >> 16) & 1)) >> 16;
    return (unsigned short)r;
}

// X (MM,C) fp32 -> H/Mo/L (MM,Cp) bf16 limbs, zero-padded cols C..Cp.
// Row-major point-major = K-contiguous, directly loadable as MFMA fragments.
__global__ void split3_kernel(const float* __restrict__ X, int C, int logCp,
                              unsigned short* __restrict__ H,
                              unsigned short* __restrict__ Mo,
                              unsigned short* __restrict__ L) {
    int t = blockIdx.x * 256 + threadIdx.x;
    int row = t >> logCp;
    int c = t & ((1 << logCp) - 1);
    float v = (c < C) ? X[(size_t)row * C + c] : 0.f;
    unsigned short hb = f2bf(v);
    float r1 = v - __uint_as_float((unsigned)hb << 16);
    unsigned short mb = f2bf(r1);
    float r2 = r1 - __uint_as_float((unsigned)mb << 16);
    unsigned short lb = f2bf(r2);
    H[t] = hb;
    Mo[t] = mb;
    L[t] = lb;
}

// ---------------------------------------------------------------- wave helpers
// Sum of per-lane 6-bit counts (0..32) across 64 lanes via ballot slices:
// 6 independent v_cmp + s_bcnt -- no DPP chains, no readlane; result uniform.
__device__ __forceinline__ int wave_sum6(int local) {
    int s = 0;
#pragma unroll
    for (int k = 0; k < 6; k++)
        s += (int)__popcll(__ballot(((local >> k) & 1) != 0)) << k;
    return s;
}

__device__ __forceinline__ unsigned long long shfl_xor_u64(unsigned long long v, int s) {
    unsigned lo = (unsigned)__shfl_xor((int)(v & 0xFFFFFFFFull), s);
    unsigned hi = (unsigned)__shfl_xor((int)(v >> 32), s);
    return ((unsigned long long)hi << 32) | lo;
}

// ---------------------------------------------------------------- kNN
// 1024-thread blocks, 16 waves, TI=16 queries. Distance phase on the matrix
// pipe (mfma_f32_16x16x32_bf16, 3-limb bf16, magnitude-split accumulators).
// Selection: register-resident radix-select (see round-6 orientation note).
// L2 RESIDENCY (round-7 fix): blocks are grouped CONTIGUOUSLY per batch
// (b = blockIdx / (NN/TI)) instead of the modulo-XCD swizzle. The swizzle
// assumed blockIdx%8 == XCD id; if that mapping doesn't hold, every XCD's
// L2 sees all 8 limb panels (12 MB > 4 MB) and thrashes to L3 -- measured
// ~7.7 TB/s effective, ~180 us of stall. With contiguous groups, the ~256
// concurrently-resident blocks span <= 2 batches (3 MB) regardless of the
// dispatcher's block->XCD rule.
template<int KIT>
__global__ __launch_bounds__(1024, 4)
void knn_kernel(const unsigned short* __restrict__ XH,
                const unsigned short* __restrict__ XM,
                const unsigned short* __restrict__ XL,
                const float* __restrict__ sq, int* __restrict__ idxout) {
    constexpr int Cp = KIT * 32;
    int b  = blockIdx.x / (NN / TI);           // contiguous block-group per batch
    int i0 = (blockIdx.x % (NN / TI)) * TI;
    int tid = threadIdx.x;
    __shared__ __align__(16) float dl[TI][NN]; // 128 KB: all 16 rows at once
    __shared__ __align__(16) float sqs[NN];    // 8 KB: batch point sq-norms

    for (int t = tid; t < NN / 4; t += 1024)
        ((float4*)sqs)[t] = ((const float4*)(sq + (size_t)b * NN))[t];

    int lane = tid & 63, wv = tid >> 6;        // wv in 0..15
    int r16 = lane & 15, kg = lane >> 4;       // kg in 0..3 (K-slice)

    // A fragments: 16 distinct query rows
    const size_t abase = ((size_t)b * NN + i0 + r16) * Cp + kg * 8;
    bf16x8 ah[KIT], am[KIT], al[KIT];
#pragma unroll
    for (int k = 0; k < KIT; k++) {
        ah[k] = *(const bf16x8*)(XH + abase + k * 32);
        am[k] = *(const bf16x8*)(XM + abase + k * 32);
        al[k] = *(const bf16x8*)(XL + abase + k * 32);
    }
    __syncthreads();                           // sqs ready

    float qsq[4];
#pragma unroll
    for (int rg = 0; rg < 4; rg++)
        qsq[rg] = sqs[i0 + kg * 4 + rg];       // query row kg*4+rg

    // ---- distance phase: wave wv covers points [wv*128, wv*128+128)
    const size_t bbase = ((size_t)b * NN + wv * 128 + r16) * Cp + kg * 8;
#pragma unroll 2
    for (int t = 0; t < 8; t++) {
        int jc = wv * 128 + t * 16 + r16;      // this lane's output column
        size_t boff = bbase + (size_t)(t * 16) * Cp;
        f32x4 accH  = {0.f, 0.f, 0.f, 0.f};
        f32x4 accL1 = {0.f, 0.f, 0.f, 0.f};
        f32x4 accL2 = {0.f, 0.f, 0.f, 0.f};
#pragma unroll
        for (int k = 0; k < KIT; k++) {        // B limbs transient: no spill
            bf16x8 bh = *(const bf16x8*)(XH + boff + k * 32);
            bf16x8 bm = *(const bf16x8*)(XM + boff + k * 32);
            bf16x8 bl = *(const bf16x8*)(XL + boff + k * 32);
            accH  = __builtin_amdgcn_mfma_f32_16x16x32_bf16(ah[k], bh, accH,  0, 0, 0);
            accL1 = __builtin_amdgcn_mfma_f32_16x16x32_bf16(ah[k], bm, accL1, 0, 0, 0);
            accL2 = __builtin_amdgcn_mfma_f32_16x16x32_bf16(am[k], bh, accL2, 0, 0, 0);
            accL1 = __builtin_amdgcn_mfma_f32_16x16x32_bf16(ah[k], bl, accL1, 0, 0, 0);
            accL2 = __builtin_amdgcn_mfma_f32_16x16x32_bf16(al[k], bh, accL2, 0, 0, 0);
            accL2 = __builtin_amdgcn_mfma_f32_16x16x32_bf16(am[k], bm, accL2, 0, 0, 0);
        }
        float sj = sqs[jc];
#pragma unroll
        for (int rg = 0; rg < 4; rg++) {       // all 64 lanes: rows 0-15
            float dot = accH[rg] + (accL1[rg] + accL2[rg]);
            dl[kg * 4 + rg][jc] = qsq[rg] + sj - 2.f * dot;
        }
    }
    __syncthreads();

    // ---- selection: wave wv owns row wv; register-resident radix-select
    constexpr int KSEL = KNN + 1;              // 33: ranks 1..33; drop rank-1
    float* dr = dl[wv];
    int row = b * NN + i0 + wv;

    // Load candidates j = lane + 64q as sortable uint keys (rows REVERSED:
    // A[31-q] = key_q, see orientation note). Track global (key, j) minimum
    // = rank-1 (idx-ascending tie-break via u64 min).
    unsigned A[32];
    unsigned long long bestp = ~0ull;
#pragma unroll
    for (int q = 0; q < 32; q++) {
        int j = lane + 64 * q;
        unsigned bits = __float_as_uint(dr[j]);
        unsigned u = bits ^ (unsigned)(((int)bits >> 31) | 0x80000000);
        A[31 - q] = u;
        unsigned long long p = ((unsigned long long)u << 32) | (unsigned)j;
        if (p < bestp) bestp = p;
    }
#pragma unroll
    for (int s = 32; s; s >>= 1) {
        unsigned long long o = shfl_xor_u64(bestp, s);
        if (o < bestp) bestp = o;
    }
    int j_drop = (int)(bestp & 0xFFFFFFFFull);

    // In-place 32x32 bit transpose (HD): A'[k] bit c = A[31-c] bit (31-k).
    unsigned mT = 0x0000FFFFu;
#pragma unroll
    for (int j = 16; j != 0; j >>= 1) {
#pragma unroll
        for (int k = 0; k < 32; k++)
            if ((k & j) == 0) {
                unsigned t = (A[k] ^ (A[k + j] >> j)) & mT;
                A[k] ^= t;
                A[k + j] ^= (t << j);
            }
        mT ^= (mT << (j >> 1));
    }
    // Now A[w] = bit-plane (31-w) of the keys; bit c of A[w] = candidate c.

    // MSB->LSB radix narrowing: amask = candidates matching prefix of the
    // 33rd-smallest key; acc_lt = candidates strictly below it.
    unsigned amask = 0xFFFFFFFFu, acc_lt = 0u;
    int need = KSEL;
#pragma unroll
    for (int w = 0; w < 32; w++) {             // w=0 is the MSB plane
        unsigned zero = amask & ~A[w];
        int cnt = wave_sum6(__popc(zero));
        if (cnt >= need) {
            amask = zero;
        } else {
            acc_lt |= zero;
            amask &= A[w];
            need -= cnt;
        }
    }

    // Ties at the threshold: take 'need' smallest j (ascending j = q-major).
    unsigned sel;
    int tot_eq = wave_sum6(__popc(amask));
    if (tot_eq == need) {
        sel = acc_lt | amask;
    } else {
        unsigned pick = 0; int base = 0;
        unsigned long long below = (1ull << lane) - 1;
#pragma unroll
        for (int q = 0; q < 32; q++) {
            bool e = ((amask >> q) & 1) != 0;
            unsigned long long bal = __ballot(e);
            int myr = base + (int)__popcll(bal & below);
            if (e && myr < need) pick |= (1u << q);
            base += (int)__popcll(bal);
        }
        sel = acc_lt | pick;
    }
    // Drop rank-1 (always selected: it is the global minimum).
    if ((j_drop & 63) == lane) sel &= ~(1u << (j_drop >> 6));

    // Pack 32 survivors: exclusive lane-prefix of counts, then bit-walk.
    int c = __popc(sel);
    int pfx = c;
#pragma unroll
    for (int s = 1; s < 64; s <<= 1) {
        int t = __shfl_up(pfx, s);
        if (lane >= s) pfx += t;
    }
    pfx -= c;
    int* outp = idxout + (size_t)row * KNN;
    unsigned m = sel; int k = 0;
    while (m) {
        int bit = __ffs(m) - 1; m &= m - 1;
        outp[pfx + k++] = lane + 64 * bit;
    }
}

// ---------------------------------------------------------------- dual GEMM
// Cc = [A1|A2] @ Wc(:, slice)          (raw, for gather-max)
// Ap = [A1|A2] @ Wa(:, slice) + bias   (self part, act applied later)
__global__ __launch_bounds__(256)
void gemm_dual(const float* __restrict__ A1, int K1,
               const float* __restrict__ A2, int K2,
               const float* __restrict__ Wc, const float* __restrict__ Wa,
               int ldw, const float* __restrict__ bias,
               float* __restrict__ Cc, float* __restrict__ Ap, int w) {
    const int Kdim = K1 + K2;
    __shared__ __align__(16) float As[16][68];
    __shared__ __align__(16) float Bs[16][136];   // [0,64)=Wc  [64,128)=Wa
    int tid = threadIdx.x;
    int tx = tid % 16, ty = tid / 16;
    int bm = blockIdx.y * 64, bn = blockIdx.x * 64;
    float accC[4][4] = {}, accA[4][4] = {};
    for (int k0 = 0; k0 < Kdim; k0 += 16) {
        for (int e = tid; e < 64 * 16; e += 256) {
            int row = e >> 4, col = e & 15;
            int k = k0 + col;
            float v = 0.f;
            if (k < K1)        v = A1[(size_t)(bm + row) * K1 + k];
            else if (k < Kdim) v = A2[(size_t)(bm + row) * K2 + (k - K1)];
            As[col][row] = v;
        }
        for (int e = tid; e < 16 * 64; e += 256) {
            int row = e >> 6, col = e & 63;
            int k = k0 + row;
            float vc = 0.f, va = 0.f;
            if (k < Kdim) {
                vc = Wc[(size_t)k * ldw + bn + col];
                va = Wa[(size_t)k * ldw + bn + col];
            }
            Bs[row][col] = vc;
            Bs[row][64 + col] = va;
        }
        __syncthreads();
#pragma unroll
        for (int kk = 0; kk < 16; kk++) {
            float4 av = *(const float4*)&As[kk][ty * 4];
            float4 bc = *(const float4*)&Bs[kk][tx * 4];
            float4 ba = *(const float4*)&Bs[kk][64 + tx * 4];
            float a[4]  = {av.x, av.y, av.z, av.w};
            float c[4]  = {bc.x, bc.y, bc.z, bc.w};
            float aa[4] = {ba.x, ba.y, ba.z, ba.w};
#pragma unroll
            for (int i = 0; i < 4; i++)
#pragma unroll
                for (int j = 0; j < 4; j++) {
                    accC[i][j] += a[i] * c[j];
                    accA[i][j] += a[i] * aa[j];
                }
        }
        __syncthreads();
    }
#pragma unroll
    for (int i = 0; i < 4; i++) {
        int row = bm + ty * 4 + i;
        int col0 = bn + tx * 4;
        float4 oc = {accC[i][0], accC[i][1], accC[i][2], accC[i][3]};
        *(float4*)&Cc[(size_t)row * w + col0] = oc;
        float4 oa = {accA[i][0] + bias[col0 + 0], accA[i][1] + bias[col0 + 1],
                     accA[i][2] + bias[col0 + 2], accA[i][3] + bias[col0 + 3]};
        *(float4*)&Ap[(size_t)row * w + col0] = oa;
    }
}

// ---------------------------------------------------------------- gather+epilogue
// out[row][col_off+ch] = act( Ap[row][ch] + max_j Cc[nbr_j][ch] )
// Blocks grouped contiguously per batch (b = L >> 11) for L2 residency of
// the Cc panel -- same mapping-robustness fix as knn_kernel.
template<int FINAL>
__global__ void gather_fuse(const float* __restrict__ Cc, const float* __restrict__ Ap,
                            const int* __restrict__ idx, int w,
                            void* __restrict__ out, int ldo, int col_off, int relu,
                            const int* __restrict__ dflag) {
    int L = blockIdx.x;
    int b = L >> 11;               // contiguous: 2048 rows per batch group
    int i = L & (NN - 1);
    int row = b * NN + i;
    int ch = threadIdx.x;
    __shared__ int sidx[KNN];
    if (ch < KNN) sidx[ch] = idx[(size_t)row * KNN + ch] & (NN - 1);
    __syncthreads();
    const float* cbase = Cc + (size_t)b * NN * w;
    float m = -3.4e38f;
#pragma unroll 4
    for (int t = 0; t < KNN; t++)
        m = fmaxf(m, cbase[(size_t)sidx[t] * w + ch]);
    float r = Ap[(size_t)row * w + ch] + m;
    if (relu) r = fmaxf(r, 0.f);
    if (FINAL) {
        r = (r != r) ? 333.0f : r;
        if (*dflag)
            ((float*)out)[(size_t)row * ldo + col_off + ch] = r;
        else
            ((__hip_bfloat16*)out)[(size_t)row * ldo + col_off + ch] = __float2bfloat16(r);
    } else {
        ((float*)out)[(size_t)row * ldo + col_off + ch] = r;
    }
}

// ---------------------------------------------------------------- launch
extern "C" void kernel_launch(void* const* d_in, const int* in_sizes, int n_in,
                              void* d_out, int out_size, void* d_ws, size_t ws_size,
                              hipStream_t stream) {
    const void* x  = d_in[0];
    const void* W1 = d_in[1];
    const void* b1 = d_in[2];
    const void* W2 = d_in[3];
    const void* b2 = d_in[4];
    const void* W3 = d_in[5];
    const void* b3 = d_in[6];

    const size_t WEIGHTS = (size_t)(3*64*2 + 64) + (64*128*2 + 128) + (192*512*2 + 512);
    const size_t fixed   = (size_t)MM*64 + (size_t)MM*128 + (size_t)MM*32 + WEIGHTS + 16;
    const size_t need64  = (fixed + (size_t)MM*2*64)  * 4;
    const size_t need128 = (fixed + (size_t)MM*2*128) * 4;

    if (d_ws == nullptr || ws_size < need64) {
        float marker = 100.0f + (float)(ws_size >> 20);
        diag_fill_kernel<<<(out_size + 255) / 256, 256, 0, stream>>>(
            (__hip_bfloat16*)d_out, out_size, marker);
        return;
    }
    const int CW = (ws_size >= need128) ? 128 : 64;

    float* ws = (float*)d_ws;
    size_t o = 0;
    float* X1   = ws + o; o += (size_t)MM * 64;
    float* X2   = ws + o; o += (size_t)MM * 128;
    float* Cc   = ws + o; o += (size_t)MM * CW;
    float* Ap   = ws + o; o += (size_t)MM * CW;
    float* Wa1  = ws + o; o += 3 * 64;
    float* Wc1  = ws + o; o += 3 * 64;
    float* bf1  = ws + o; o += 64;
    float* Wa2  = ws + o; o += 64 * 128;
    float* Wc2  = ws + o; o += 64 * 128;
    float* bf2  = ws + o; o += 128;
    float* Wa3  = ws + o; o += 192 * 512;
    float* Wc3  = ws + o; o += 192 * 512;
    float* bf3  = ws + o; o += 512;
    int*   idxb = (int*)(ws + o); o += (size_t)MM * KNN;
    int*   dflag = (int*)(ws + o); o += 16;

    // bf16-limb arrays / X0 / SQ live in d_out: dead before any final output
    // write (knn of a stage completes before that stage's gather_fuse runs).
    unsigned short* XH  = (unsigned short*)d_out;        // MM*128 ush = 4 MB
    unsigned short* XMD = XH  + (size_t)MM * 128;        // 4 MB
    unsigned short* XLO = XMD + (size_t)MM * 128;        // 4 MB
    float* X0 = (float*)(XLO + (size_t)MM * 128);        // MM*3 floats
    float* SQ = X0 + (size_t)MM * 3;                     // MM floats

    // dtype detect + prep
    detect_dtype_kernel<<<1, 256, 0, stream>>>((const unsigned short*)x, 24576, dflag);
    upcast_kernel<<<(MM * 3 + 255) / 256, 256, 0, stream>>>(x, X0, MM * 3, dflag);
    prep_w_kernel<<<1,   256, 0, stream>>>(W1, b1, Wa1, Wc1, bf1, 3, 64, dflag);
    prep_w_kernel<<<32,  256, 0, stream>>>(W2, b2, Wa2, Wc2, bf2, 64, 128, dflag);
    prep_w_kernel<<<384, 256, 0, stream>>>(W3, b3, Wa3, Wc3, bf3, 192, 512, dflag);

    // Chunked EdgeConv tail: per chunk of width w:
    //   gemm_dual: Cc = X@Wc_slice, Ap = X@Wa_slice + b
    //   gather_fuse: out = act(Ap + gather-max(Cc))
    auto edge_tail = [&](const float* A1, int K1, const float* A2, int K2,
                         const float* Wa, const float* Wc, const float* bfp, int Cout,
                         void* outp, int ldo, int relu, bool final) {
        for (int n0 = 0; n0 < Cout; ) {
            int w = Cout - n0 < CW ? Cout - n0 : CW;
            dim3 g(w / 64, MM / 64);
            gemm_dual<<<g, 256, 0, stream>>>(A1, K1, A2, K2, Wc + n0, Wa + n0,
                                             Cout, bfp + n0, Cc, Ap, w);
            if (final)
                gather_fuse<1><<<MM, w, 0, stream>>>(Cc, Ap, idxb, w, outp, ldo,
                                                     n0, relu, dflag);
            else
                gather_fuse<0><<<MM, w, 0, stream>>>(Cc, Ap, idxb, w, outp, ldo,
                                                     n0, relu, dflag);
            n0 += w;
        }
    };

    // ---- stage 1 (C=3 -> 64); Cp=32
    sqnorm_kernel<<<MM / 256, 256, 0, stream>>>(X0, SQ, 3);
    split3_kernel<<<(MM * 32) / 256, 256, 0, stream>>>(X0, 3, 5, XH, XMD, XLO);
    knn_kernel<1><<<MM / TI, 1024, 0, stream>>>(XH, XMD, XLO, SQ, idxb);
    edge_tail(X0, 3, nullptr, 0, Wa1, Wc1, bf1, 64, (void*)X1, 64, 1, false);

    // ---- stage 2 (C=64 -> 128)
    sqnorm_kernel<<<MM / 256, 256, 0, stream>>>(X1, SQ, 64);
    split3_kernel<<<(MM * 64) / 256, 256, 0, stream>>>(X1, 64, 6, XH, XMD, XLO);
    knn_kernel<2><<<MM / TI, 1024, 0, stream>>>(XH, XMD, XLO, SQ, idxb);
    edge_tail(X1, 64, nullptr, 0, Wa2, Wc2, bf2, 128, (void*)X2, 128, 1, false);

    // ---- stage 3 (C=192 = [X1|X2] -> 512, no relu, final out; knn on X2)
    sqnorm_kernel<<<MM / 256, 256, 0, stream>>>(X2, SQ, 128);
    split3_kernel<<<(MM * 128) / 256, 256, 0, stream>>>(X2, 128, 7, XH, XMD, XLO);
    knn_kernel<4><<<MM / TI, 1024, 0, stream>>>(XH, XMD, XLO, SQ, idxb);
    edge_tail(X1, 64, X2, 128, Wa3, Wc3, bf3, 512, d_out, 512, 0, true);
}

// Round 9
// 970.150 us; speedup vs baseline: 1.0042x; 1.0042x over previous
//
#include <hip/hip_runtime.h>
#include <hip/hip_bf16.h>

#define BB 8
#define NN 2048
#define MM (BB*NN)
#define KNN 32
#define TI 16

typedef __bf16 bf16x8 __attribute__((ext_vector_type(8)));
typedef float  f32x4  __attribute__((ext_vector_type(4)));

// ---------------------------------------------------------------- dtype detect
__global__ void detect_dtype_kernel(const unsigned short* __restrict__ p,
                                    int n16, int* __restrict__ flag) {
    __shared__ int cnt;
    if (threadIdx.x == 0) cnt = 0;
    __syncthreads();
    int local = 0;
    for (int i = threadIdx.x; i < n16; i += 256) {
        int e = (p[i] >> 7) & 0xFF;
        if (e >= 132) local++;     // |v| >= 2^5, or inf/nan
    }
    atomicAdd(&cnt, local);
    __syncthreads();
    if (threadIdx.x == 0) *flag = (cnt > 100) ? 1 : 0;   // 1 = fp32 inputs
}

// ---------------------------------------------------------------- diagnostic
__global__ void diag_fill_kernel(__hip_bfloat16* __restrict__ out, int n, float marker) {
    int i = blockIdx.x * 256 + threadIdx.x;
    if (i < n) out[i] = __float2bfloat16(marker);
}

// ---------------------------------------------------------------- utilities
__global__ void upcast_kernel(const void* __restrict__ in, float* __restrict__ out,
                              int n, const int* __restrict__ flag) {
    int f32 = *flag;
    int i = blockIdx.x * 256 + threadIdx.x;
    if (i < n)
        out[i] = f32 ? ((const float*)in)[i]
                     : __bfloat162float(((const __hip_bfloat16*)in)[i]);
}

// W: (2C, Cout) -> Wa = Wtop - Wbot, Wc = Wbot (C x Cout fp32), bf = bias.
// EdgeConv decomposition:
//   max_j act([x_i, x_j - x_i] W + b) = act(x_i Wa + b + max_j (x_j Wc))
__global__ void prep_w_kernel(const void* __restrict__ W, const void* __restrict__ bvec,
                              float* __restrict__ Wa, float* __restrict__ Wc,
                              float* __restrict__ bf, int C, int Cout,
                              const int* __restrict__ flag) {
    int f32 = *flag;
    int total = C * Cout;
    int gid = blockIdx.x * 256 + threadIdx.x;
    for (int t = gid; t < total; t += gridDim.x * 256) {
        int k = t / Cout, n = t % Cout;
        float top, bot;
        if (f32) {
            top = ((const float*)W)[k * Cout + n];
            bot = ((const float*)W)[(C + k) * Cout + n];
        } else {
            top = __bfloat162float(((const __hip_bfloat16*)W)[k * Cout + n]);
            bot = __bfloat162float(((const __hip_bfloat16*)W)[(C + k) * Cout + n]);
        }
        Wa[t] = top - bot;
        Wc[t] = bot;
    }
    if (gid < Cout)
        bf[gid] = f32 ? ((const float*)bvec)[gid]
                      : __bfloat162float(((const __hip_bfloat16*)bvec)[gid]);
}

__global__ void sqnorm_kernel(const float* __restrict__ X, float* __restrict__ sq, int C) {
    int row = blockIdx.x * 256 + threadIdx.x;
    if (row < MM) {
        float s = 0.f;
        for (int c = 0; c < C; c++) { float v = X[(size_t)row * C + c]; s += v * v; }
        sq[row] = s;
    }
}

// ---------------------------------------------------------------- bf16 3-way split
// x = h + m + l with each limb bf16 (RNE); residual ~2^-27 relative.
// Products kept: hh (full magnitude) + hm,mh,hl,lh,mm (<= 2^-9 magnitude).
__device__ __forceinline__ unsigned short f2bf(float f) {
    unsigned u = __float_as_uint(f);
    unsigned r = (u + 0x7FFF + ((u >> 16) & 1)) >> 16;
    return (unsigned short)r;
}

// X (MM,C) fp32 -> H/Mo/L (MM,Cp) bf16 limbs, zero-padded cols C..Cp.
// Row-major point-major = K-contiguous, directly loadable as MFMA fragments.
__global__ void split3_kernel(const float* __restrict__ X, int C, int logCp,
                              unsigned short* __restrict__ H,
                              unsigned short* __restrict__ Mo,
                              unsigned short* __restrict__ L) {
    int t = blockIdx.x * 256 + threadIdx.x;
    int row = t >> logCp;
    int c = t & ((1 << logCp) - 1);
    float v = (c < C) ? X[(size_t)row * C + c] : 0.f;
    unsigned short hb = f2bf(v);
    float r1 = v - __uint_as_float((unsigned)hb << 16);
    unsigned short mb = f2bf(r1);
    float r2 = r1 - __uint_as_float((unsigned)mb << 16);
    unsigned short lb = f2bf(r2);
    H[t] = hb;
    Mo[t] = mb;
    L[t] = lb;
}

// ---------------------------------------------------------------- wave helpers
// Sum of per-lane 6-bit counts (0..32) across 64 lanes via ballot slices:
// 6 independent v_cmp + s_bcnt -- no DPP chains, no readlane; result uniform.
__device__ __forceinline__ int wave_sum6(int local) {
    int s = 0;
#pragma unroll
    for (int k = 0; k < 6; k++)
        s += (int)__popcll(__ballot(((local >> k) & 1) != 0)) << k;
    return s;
}

__device__ __forceinline__ unsigned long long shfl_xor_u64(unsigned long long v, int s) {
    unsigned lo = (unsigned)__shfl_xor((int)(v & 0xFFFFFFFFull), s);
    unsigned hi = (unsigned)__shfl_xor((int)(v >> 32), s);
    return ((unsigned long long)hi << 32) | lo;
}

// ---------------------------------------------------------------- kNN
// 1024-thread blocks, 16 waves, TI=16 queries. Distance phase on the matrix
// pipe (mfma_f32_16x16x32_bf16, 3-limb bf16, magnitude-split accumulators).
// Selection: register-resident radix-select (round-6 orientation note).
// ROUND-9 FIX (register-starved load serialization): rounds 5-8 allocated
// only 52 VGPRs -- too few to keep the 12 B-limb loads in flight, so the
// compiler serialized them (waitcnt between 2-3-deep load groups), exposing
// ~200-900cy latency per group; duration was invariant to HBM/L2 traffic
// (r7 vs r8: 8x fetch change, same 244us) because the limiter was schedule,
// not bandwidth. Coercion: load all 12 B vectors into named locals, then
// sched_barrier(0) -- no MFMA may be hoisted above, so all 12 must be
// co-live (48 VGPRs) and issue breadth-first. launch_bounds(1024,4) gives a
// 128-VGPR budget (LDS already caps us at 1 block = 4 waves/SIMD).
// Accumulators rebalanced to 4 chains (max MFMA dep depth 12 -> 8; hh still
// isolated in accH for fp32-class precision).
template<int KIT>
__global__ __launch_bounds__(1024, 4)
void knn_kernel(const unsigned short* __restrict__ XH,
                const unsigned short* __restrict__ XM,
                const unsigned short* __restrict__ XL,
                const float* __restrict__ sq, int* __restrict__ idxout) {
    constexpr int Cp = KIT * 32;
    int b = blockIdx.x & 7;                    // round-7 mapping (lower HBM)
    int i0 = (blockIdx.x >> 3) * TI;
    int tid = threadIdx.x;
    __shared__ __align__(16) float dl[TI][NN]; // 128 KB: all 16 rows at once
    __shared__ __align__(16) float sqs[NN];    // 8 KB: batch point sq-norms

    for (int t = tid; t < NN / 4; t += 1024)
        ((float4*)sqs)[t] = ((const float4*)(sq + (size_t)b * NN))[t];

    int lane = tid & 63, wv = tid >> 6;        // wv in 0..15
    int r16 = lane & 15, kg = lane >> 4;       // kg in 0..3 (K-slice)

    // A fragments: 16 distinct query rows (loop-invariant, register-resident)
    const size_t abase = ((size_t)b * NN + i0 + r16) * Cp + kg * 8;
    bf16x8 ah[KIT], am[KIT], al[KIT];
#pragma unroll
    for (int k = 0; k < KIT; k++) {
        ah[k] = *(const bf16x8*)(XH + abase + k * 32);
        am[k] = *(const bf16x8*)(XM + abase + k * 32);
        al[k] = *(const bf16x8*)(XL + abase + k * 32);
    }
    __syncthreads();                           // sqs ready

    float qsq[4];
#pragma unroll
    for (int rg = 0; rg < 4; rg++)
        qsq[rg] = sqs[i0 + kg * 4 + rg];       // query row kg*4+rg

    // ---- distance phase: wave wv covers points [wv*128, wv*128+128)
    const size_t bbase = ((size_t)b * NN + wv * 128 + r16) * Cp + kg * 8;
#pragma unroll 1
    for (int t = 0; t < 8; t++) {
        int jc = wv * 128 + t * 16 + r16;      // this lane's output column
        size_t boff = bbase + (size_t)(t * 16) * Cp;
        bf16x8 bh[KIT], bm[KIT], bl[KIT];
#pragma unroll
        for (int k = 0; k < KIT; k++) {        // all 12 loads issued first
            bh[k] = *(const bf16x8*)(XH + boff + k * 32);
            bm[k] = *(const bf16x8*)(XM + boff + k * 32);
            bl[k] = *(const bf16x8*)(XL + boff + k * 32);
        }
        __builtin_amdgcn_sched_barrier(0);     // keep loads above all MFMAs
        f32x4 accH  = {0.f, 0.f, 0.f, 0.f};
        f32x4 accL1 = {0.f, 0.f, 0.f, 0.f};
        f32x4 accL2 = {0.f, 0.f, 0.f, 0.f};
        f32x4 accL3 = {0.f, 0.f, 0.f, 0.f};
#pragma unroll
        for (int k = 0; k < KIT; k++) {        // 4 chains: depth <= 8
            accH  = __builtin_amdgcn_mfma_f32_16x16x32_bf16(ah[k], bh[k], accH,  0, 0, 0);
            accL1 = __builtin_amdgcn_mfma_f32_16x16x32_bf16(ah[k], bm[k], accL1, 0, 0, 0);
            accL2 = __builtin_amdgcn_mfma_f32_16x16x32_bf16(am[k], bh[k], accL2, 0, 0, 0);
            accL1 = __builtin_amdgcn_mfma_f32_16x16x32_bf16(ah[k], bl[k], accL1, 0, 0, 0);
            accL2 = __builtin_amdgcn_mfma_f32_16x16x32_bf16(al[k], bh[k], accL2, 0, 0, 0);
            accL3 = __builtin_amdgcn_mfma_f32_16x16x32_bf16(am[k], bm[k], accL3, 0, 0, 0);
        }
        float sj = sqs[jc];
#pragma unroll
        for (int rg = 0; rg < 4; rg++) {       // all 64 lanes: rows 0-15
            float dot = accH[rg] + ((accL1[rg] + accL2[rg]) + accL3[rg]);
            dl[kg * 4 + rg][jc] = qsq[rg] + sj - 2.f * dot;
        }
    }
    __syncthreads();

    // ---- selection: wave wv owns row wv; register-resident radix-select
    constexpr int KSEL = KNN + 1;              // 33: ranks 1..33; drop rank-1
    float* dr = dl[wv];
    int row = b * NN + i0 + wv;

    // Load candidates j = lane + 64q as sortable uint keys (rows REVERSED:
    // A[31-q] = key_q, see orientation note). Track global (key, j) minimum
    // = rank-1 (idx-ascending tie-break via u64 min).
    unsigned A[32];
    unsigned long long bestp = ~0ull;
#pragma unroll
    for (int q = 0; q < 32; q++) {
        int j = lane + 64 * q;
        unsigned bits = __float_as_uint(dr[j]);
        unsigned u = bits ^ (unsigned)(((int)bits >> 31) | 0x80000000);
        A[31 - q] = u;
        unsigned long long p = ((unsigned long long)u << 32) | (unsigned)j;
        if (p < bestp) bestp = p;
    }
#pragma unroll
    for (int s = 32; s; s >>= 1) {
        unsigned long long o = shfl_xor_u64(bestp, s);
        if (o < bestp) bestp = o;
    }
    int j_drop = (int)(bestp & 0xFFFFFFFFull);

    // In-place 32x32 bit transpose (HD): A'[k] bit c = A[31-c] bit (31-k).
    unsigned mT = 0x0000FFFFu;
#pragma unroll
    for (int j = 16; j != 0; j >>= 1) {
#pragma unroll
        for (int k = 0; k < 32; k++)
            if ((k & j) == 0) {
                unsigned t = (A[k] ^ (A[k + j] >> j)) & mT;
                A[k] ^= t;
                A[k + j] ^= (t << j);
            }
        mT ^= (mT << (j >> 1));
    }
    // Now A[w] = bit-plane (31-w) of the keys; bit c of A[w] = candidate c.

    // MSB->LSB radix narrowing: amask = candidates matching prefix of the
    // 33rd-smallest key; acc_lt = candidates strictly below it.
    unsigned amask = 0xFFFFFFFFu, acc_lt = 0u;
    int need = KSEL;
#pragma unroll
    for (int w = 0; w < 32; w++) {             // w=0 is the MSB plane
        unsigned zero = amask & ~A[w];
        int cnt = wave_sum6(__popc(zero));
        if (cnt >= need) {
            amask = zero;
        } else {
            acc_lt |= zero;
            amask &= A[w];
            need -= cnt;
        }
    }

    // Ties at the threshold: take 'need' smallest j (ascending j = q-major).
    unsigned sel;
    int tot_eq = wave_sum6(__popc(amask));
    if (tot_eq == need) {
        sel = acc_lt | amask;
    } else {
        unsigned pick = 0; int base = 0;
        unsigned long long below = (1ull << lane) - 1;
#pragma unroll
        for (int q = 0; q < 32; q++) {
            bool e = ((amask >> q) & 1) != 0;
            unsigned long long bal = __ballot(e);
            int myr = base + (int)__popcll(bal & below);
            if (e && myr < need) pick |= (1u << q);
            base += (int)__popcll(bal);
        }
        sel = acc_lt | pick;
    }
    // Drop rank-1 (always selected: it is the global minimum).
    if ((j_drop & 63) == lane) sel &= ~(1u << (j_drop >> 6));

    // Pack 32 survivors: exclusive lane-prefix of counts, then bit-walk.
    int c = __popc(sel);
    int pfx = c;
#pragma unroll
    for (int s = 1; s < 64; s <<= 1) {
        int t = __shfl_up(pfx, s);
        if (lane >= s) pfx += t;
    }
    pfx -= c;
    int* outp = idxout + (size_t)row * KNN;
    unsigned m = sel; int k = 0;
    while (m) {
        int bit = __ffs(m) - 1; m &= m - 1;
        outp[pfx + k++] = lane + 64 * bit;
    }
}

// ---------------------------------------------------------------- dual GEMM
// Cc = [A1|A2] @ Wc(:, slice)          (raw, for gather-max)
// Ap = [A1|A2] @ Wa(:, slice) + bias   (self part, act applied later)
__global__ __launch_bounds__(256)
void gemm_dual(const float* __restrict__ A1, int K1,
               const float* __restrict__ A2, int K2,
               const float* __restrict__ Wc, const float* __restrict__ Wa,
               int ldw, const float* __restrict__ bias,
               float* __restrict__ Cc, float* __restrict__ Ap, int w) {
    const int Kdim = K1 + K2;
    __shared__ __align__(16) float As[16][68];
    __shared__ __align__(16) float Bs[16][136];   // [0,64)=Wc  [64,128)=Wa
    int tid = threadIdx.x;
    int tx = tid % 16, ty = tid / 16;
    int bm = blockIdx.y * 64, bn = blockIdx.x * 64;
    float accC[4][4] = {}, accA[4][4] = {};
    for (int k0 = 0; k0 < Kdim; k0 += 16) {
        for (int e = tid; e < 64 * 16; e += 256) {
            int row = e >> 4, col = e & 15;
            int k = k0 + col;
            float v = 0.f;
            if (k < K1)        v = A1[(size_t)(bm + row) * K1 + k];
            else if (k < Kdim) v = A2[(size_t)(bm + row) * K2 + (k - K1)];
            As[col][row] = v;
        }
        for (int e = tid; e < 16 * 64; e += 256) {
            int row = e >> 6, col = e & 63;
            int k = k0 + row;
            float vc = 0.f, va = 0.f;
            if (k < Kdim) {
                vc = Wc[(size_t)k * ldw + bn + col];
                va = Wa[(size_t)k * ldw + bn + col];
            }
            Bs[row][col] = vc;
            Bs[row][64 + col] = va;
        }
        __syncthreads();
#pragma unroll
        for (int kk = 0; kk < 16; kk++) {
            float4 av = *(const float4*)&As[kk][ty * 4];
            float4 bc = *(const float4*)&Bs[kk][tx * 4];
            float4 ba = *(const float4*)&Bs[kk][64 + tx * 4];
            float a[4]  = {av.x, av.y, av.z, av.w};
            float c[4]  = {bc.x, bc.y, bc.z, bc.w};
            float aa[4] = {ba.x, ba.y, ba.z, ba.w};
#pragma unroll
            for (int i = 0; i < 4; i++)
#pragma unroll
                for (int j = 0; j < 4; j++) {
                    accC[i][j] += a[i] * c[j];
                    accA[i][j] += a[i] * aa[j];
                }
        }
        __syncthreads();
    }
#pragma unroll
    for (int i = 0; i < 4; i++) {
        int row = bm + ty * 4 + i;
        int col0 = bn + tx * 4;
        float4 oc = {accC[i][0], accC[i][1], accC[i][2], accC[i][3]};
        *(float4*)&Cc[(size_t)row * w + col0] = oc;
        float4 oa = {accA[i][0] + bias[col0 + 0], accA[i][1] + bias[col0 + 1],
                     accA[i][2] + bias[col0 + 2], accA[i][3] + bias[col0 + 3]};
        *(float4*)&Ap[(size_t)row * w + col0] = oa;
    }
}

// ---------------------------------------------------------------- gather+epilogue
// out[row][col_off+ch] = act( Ap[row][ch] + max_j Cc[nbr_j][ch] )
template<int FINAL>
__global__ void gather_fuse(const float* __restrict__ Cc, const float* __restrict__ Ap,
                            const int* __restrict__ idx, int w,
                            void* __restrict__ out, int ldo, int col_off, int relu,
                            const int* __restrict__ dflag) {
    int L = blockIdx.x;
    int b = L & 7;                 // round-7 mapping
    int i = L >> 3;
    int row = b * NN + i;
    int ch = threadIdx.x;
    __shared__ int sidx[KNN];
    if (ch < KNN) sidx[ch] = idx[(size_t)row * KNN + ch] & (NN - 1);
    __syncthreads();
    const float* cbase = Cc + (size_t)b * NN * w;
    float m = -3.4e38f;
#pragma unroll 4
    for (int t = 0; t < KNN; t++)
        m = fmaxf(m, cbase[(size_t)sidx[t] * w + ch]);
    float r = Ap[(size_t)row * w + ch] + m;
    if (relu) r = fmaxf(r, 0.f);
    if (FINAL) {
        r = (r != r) ? 333.0f : r;
        if (*dflag)
            ((float*)out)[(size_t)row * ldo + col_off + ch] = r;
        else
            ((__hip_bfloat16*)out)[(size_t)row * ldo + col_off + ch] = __float2bfloat16(r);
    } else {
        ((float*)out)[(size_t)row * ldo + col_off + ch] = r;
    }
}

// ---------------------------------------------------------------- launch
extern "C" void kernel_launch(void* const* d_in, const int* in_sizes, int n_in,
                              void* d_out, int out_size, void* d_ws, size_t ws_size,
                              hipStream_t stream) {
    const void* x  = d_in[0];
    const void* W1 = d_in[1];
    const void* b1 = d_in[2];
    const void* W2 = d_in[3];
    const void* b2 = d_in[4];
    const void* W3 = d_in[5];
    const void* b3 = d_in[6];

    const size_t WEIGHTS = (size_t)(3*64*2 + 64) + (64*128*2 + 128) + (192*512*2 + 512);
    const size_t fixed   = (size_t)MM*64 + (size_t)MM*128 + (size_t)MM*32 + WEIGHTS + 16;
    const size_t need64  = (fixed + (size_t)MM*2*64)  * 4;
    const size_t need128 = (fixed + (size_t)MM*2*128) * 4;

    if (d_ws == nullptr || ws_size < need64) {
        float marker = 100.0f + (float)(ws_size >> 20);
        diag_fill_kernel<<<(out_size + 255) / 256, 256, 0, stream>>>(
            (__hip_bfloat16*)d_out, out_size, marker);
        return;
    }
    const int CW = (ws_size >= need128) ? 128 : 64;

    float* ws = (float*)d_ws;
    size_t o = 0;
    float* X1   = ws + o; o += (size_t)MM * 64;
    float* X2   = ws + o; o += (size_t)MM * 128;
    float* Cc   = ws + o; o += (size_t)MM * CW;
    float* Ap   = ws + o; o += (size_t)MM * CW;
    float* Wa1  = ws + o; o += 3 * 64;
    float* Wc1  = ws + o; o += 3 * 64;
    float* bf1  = ws + o; o += 64;
    float* Wa2  = ws + o; o += 64 * 128;
    float* Wc2  = ws + o; o += 64 * 128;
    float* bf2  = ws + o; o += 128;
    float* Wa3  = ws + o; o += 192 * 512;
    float* Wc3  = ws + o; o += 192 * 512;
    float* bf3  = ws + o; o += 512;
    int*   idxb = (int*)(ws + o); o += (size_t)MM * KNN;
    int*   dflag = (int*)(ws + o); o += 16;

    // bf16-limb arrays / X0 / SQ live in d_out: dead before any final output
    // write (knn of a stage completes before that stage's gather_fuse runs).
    unsigned short* XH  = (unsigned short*)d_out;        // MM*128 ush = 4 MB
    unsigned short* XMD = XH  + (size_t)MM * 128;        // 4 MB
    unsigned short* XLO = XMD + (size_t)MM * 128;        // 4 MB
    float* X0 = (float*)(XLO + (size_t)MM * 128);        // MM*3 floats
    float* SQ = X0 + (size_t)MM * 3;                     // MM floats

    // dtype detect + prep
    detect_dtype_kernel<<<1, 256, 0, stream>>>((const unsigned short*)x, 24576, dflag);
    upcast_kernel<<<(MM * 3 + 255) / 256, 256, 0, stream>>>(x, X0, MM * 3, dflag);
    prep_w_kernel<<<1,   256, 0, stream>>>(W1, b1, Wa1, Wc1, bf1, 3, 64, dflag);
    prep_w_kernel<<<32,  256, 0, stream>>>(W2, b2, Wa2, Wc2, bf2, 64, 128, dflag);
    prep_w_kernel<<<384, 256, 0, stream>>>(W3, b3, Wa3, Wc3, bf3, 192, 512, dflag);

    // Chunked EdgeConv tail: per chunk of width w:
    //   gemm_dual: Cc = X@Wc_slice, Ap = X@Wa_slice + b
    //   gather_fuse: out = act(Ap + gather-max(Cc))
    auto edge_tail = [&](const float* A1, int K1, const float* A2, int K2,
                         const float* Wa, const float* Wc, const float* bfp, int Cout,
                         void* outp, int ldo, int relu, bool final) {
        for (int n0 = 0; n0 < Cout; ) {
            int w = Cout - n0 < CW ? Cout - n0 : CW;
            dim3 g(w / 64, MM / 64);
            gemm_dual<<<g, 256, 0, stream>>>(A1, K1, A2, K2, Wc + n0, Wa + n0,
                                             Cout, bfp + n0, Cc, Ap, w);
            if (final)
                gather_fuse<1><<<MM, w, 0, stream>>>(Cc, Ap, idxb, w, outp, ldo,
                                                     n0, relu, dflag);
            else
                gather_fuse<0><<<MM, w, 0, stream>>>(Cc, Ap, idxb, w, outp, ldo,
                                                     n0, relu, dflag);
            n0 += w;
        }
    };

    // ---- stage 1 (C=3 -> 64); Cp=32
    sqnorm_kernel<<<MM / 256, 256, 0, stream>>>(X0, SQ, 3);
    split3_kernel<<<(MM * 32) / 256, 256, 0, stream>>>(X0, 3, 5, XH, XMD, XLO);
    knn_kernel<1><<<MM / TI, 1024, 0, stream>>>(XH, XMD, XLO, SQ, idxb);
    edge_tail(X0, 3, nullptr, 0, Wa1, Wc1, bf1, 64, (void*)X1, 64, 1, false);

    // ---- stage 2 (C=64 -> 128)
    sqnorm_kernel<<<MM / 256, 256, 0, stream>>>(X1, SQ, 64);
    split3_kernel<<<(MM * 64) / 256, 256, 0, stream>>>(X1, 64, 6, XH, XMD, XLO);
    knn_kernel<2><<<MM / TI, 1024, 0, stream>>>(XH, XMD, XLO, SQ, idxb);
    edge_tail(X1, 64, nullptr, 0, Wa2, Wc2, bf2, 128, (void*)X2, 128, 1, false);

    // ---- stage 3 (C=192 = [X1|X2] -> 512, no relu, final out; knn on X2)
    sqnorm_kernel<<<MM / 256, 256, 0, stream>>>(X2, SQ, 128);
    split3_kernel<<<(MM * 128) / 256, 256, 0, stream>>>(X2, 128, 7, XH, XMD, XLO);
    knn_kernel<4><<<MM / TI, 1024, 0, stream>>>(XH, XMD, XLO, SQ, idxb);
    edge_tail(X1, 64, X2, 128, Wa3, Wc3, bf3, 512, d_out, 512, 0, true);
}